// Round 14
// baseline (28.530 us; speedup 1.0000x reference)
//
#include <hip/hip_runtime.h>

#define T_LEN  512
#define K_LEN  64
#define NFILT  32
#define NBATCH 64
#define XOFS   64                // pad: min element index = XOFS-63 >= 1
#define XS_SZ  656               // max read idx = XOFS + 582 = 646, padded
#define CHUNK  32
#define SQRT_LOG2E 1.2011224087864498f
#define LN2        0.6931471805599453f

typedef __attribute__((ext_vector_type(2))) float f32x2;

// result[lane] = src[lane-1], lane0 -> 0 (DPP wave_shr:1, bound_ctrl=1)
static __device__ __forceinline__ float wave_shr1(float x) {
    int r = __builtin_amdgcn_update_dpp(0, __builtin_bit_cast(int, x),
                                        0x138, 0xF, 0xF, true);
    return __builtin_bit_cast(float, r);
}

static __device__ __forceinline__ f32x2 wave_shr1_x2(f32x2 v) {
    f32x2 r;
    r.x = wave_shr1(v.x);
    r.y = wave_shr1(v.y);
    return r;
}

template <int N>
static __device__ __forceinline__ float row_ror(float x) {
    int r = __builtin_amdgcn_update_dpp(0, __builtin_bit_cast(int, x),
                                        0x120 + N, 0xF, 0xF, true);
    return __builtin_bit_cast(float, r);
}

static __device__ __forceinline__ float exp2_fast(float x) {
#if __has_builtin(__builtin_amdgcn_exp2f)
    return __builtin_amdgcn_exp2f(x);
#else
    return exp2f(x);
#endif
}

// Linear-domain band-limited soft-DTW, 2 problems/wave (f, f+16; same b),
// 1024 waves. Z = 2^S2 * exp(-D);
// Z[i,j] = exp(-C[i,j]) * (Z[i-1,j] + Z[i,j-1] + Z[i-1,j-1]).
//
// R14: SAME dataflow as R12 (proven absmax 0) but ROLLED: 17 iterations of a
// ~3KB 32-step body instead of a 50-70KB fully-unrolled kernel. Tests the
// I$-streaming hypothesis (the one variable R5-R13 never changed). x comes
// through an 8-deep rotating register pipeline: step s consumes xr[s&7] and
// issues the ds_read for step s+8 (slack ~8 steps >> 120cy LDS latency).
__global__ __launch_bounds__(256) void dtw_kernel(const float* __restrict__ x,
                                                  const float* __restrict__ protos,
                                                  float* __restrict__ out) {
    __shared__ float xs[XS_SZ];
    const int tid  = threadIdx.x;
    const int lane = tid & 63;
    const int wid  = tid >> 6;
    const int b    = blockIdx.x >> 2;               // 256 blocks: 4 per b
    const int fA   = ((blockIdx.x & 3) << 2) | wid; // 0..15
    const int fB   = fA + 16;

    for (int t0 = tid; t0 < XS_SZ; t0 += 256) {
        int i = t0 - XOFS;
        xs[t0] = (i >= 0 && i < T_LEN) ? x[b * T_LEN + i] * SQRT_LOG2E : 0.0f;
    }
    __syncthreads();

    const float pAn = -protos[fA * K_LEN + lane] * SQRT_LOG2E;
    const float pBn = -protos[fB * K_LEN + lane] * SQRT_LOG2E;
    const float jj  = (float)lane / 63.0f;

    // exact fp32 band interval per column (same predicate as reference)
    int a0 = 0, b0 = T_LEN - 1;
    while (a0 < b0) { int m = (a0 + b0) >> 1;
        if ((float)m / 511.0f - jj >= -0.2f) b0 = m; else a0 = m + 1; }
    const int ilo = a0;
    a0 = 0; b0 = T_LEN - 1;
    while (a0 < b0) { int m = (a0 + b0 + 1) >> 1;
        if ((float)m / 511.0f - jj <= 0.2f) a0 = m; else b0 = m - 1; }
    const int ihi = a0;

    const unsigned range = (unsigned)(ihi - ilo);
    unsigned t = (unsigned)(-(lane + ilo));
    f32x2 prev2 = {0.0f, 0.0f};
    const float d0 = (lane == 0) ? 1.0f : 0.0f;     // Z[-1,-1] = 1
    f32x2 dgp2 = {d0, d0};
    int   S2A = 0, S2B = 0;

    const float* __restrict__ xp = &xs[XOFS - lane];

    // 8-deep x register pipeline: xr holds values for steps cb+s .. cb+s+7
    float xr[8];
#pragma unroll
    for (int i = 0; i < 8; ++i) xr[i] = xp[i];

    // step: consume xr[s&7], then prefetch step cb+s+8 into the same slot
#define STEP(CB, S) do {                                      \
        float xv_  = xr[(S) & 7];                             \
        xr[(S) & 7] = xp[(CB) + (S) + 8];                     \
        float sel_ = (t <= range) ? 0.0f : -3.0e38f;          \
        ++t;                                                  \
        float dA_ = xv_ + pAn;                                \
        float dB_ = xv_ + pBn;                                \
        f32x2 w2_;                                            \
        w2_.x = exp2_fast(__builtin_fmaf(dA_, -dA_, sel_));   \
        w2_.y = exp2_fast(__builtin_fmaf(dB_, -dB_, sel_));   \
        f32x2 l2_ = wave_shr1_x2(prev2);                      \
        f32x2 a2_ = prev2 + dgp2;                             \
        f32x2 s2_ = a2_ + l2_;                                \
        dgp2  = l2_;                                          \
        prev2 = s2_ * w2_;                                    \
    } while (0)

    // wave-uniform power-of-2 renorm to max ~ 2^30 (Me = 284-e), cadence 32
#define RENORM_HALF(PVE, DGE, S2) do {                                       \
        float m_ = prev2.PVE;                                                \
        m_ = fmaxf(m_, row_ror<8>(m_));                                      \
        m_ = fmaxf(m_, row_ror<4>(m_));                                      \
        m_ = fmaxf(m_, row_ror<2>(m_));                                      \
        m_ = fmaxf(m_, row_ror<1>(m_));                                      \
        int mi_ = __builtin_bit_cast(int, m_);                               \
        unsigned r0_ = (unsigned)__builtin_amdgcn_readlane(mi_, 0);          \
        unsigned r1_ = (unsigned)__builtin_amdgcn_readlane(mi_, 16);         \
        unsigned r2_ = (unsigned)__builtin_amdgcn_readlane(mi_, 32);         \
        unsigned r3_ = (unsigned)__builtin_amdgcn_readlane(mi_, 48);         \
        unsigned ra_ = r0_ > r1_ ? r0_ : r1_;                                \
        unsigned rb_ = r2_ > r3_ ? r2_ : r3_;                                \
        unsigned mx_ = ra_ > rb_ ? ra_ : rb_;                                \
        int e_  = (int)((mx_ >> 23) & 0xFF);                                 \
        int Me_ = 284 - e_;                                                  \
        Me_ = Me_ < 1 ? 1 : (Me_ > 254 ? 254 : Me_);                         \
        float M_ = __builtin_bit_cast(float, Me_ << 23);                     \
        S2 += Me_ - 127;                                                     \
        prev2.PVE *= M_;                                                     \
        dgp2.DGE  *= M_;                                                     \
    } while (0)

#define RENORM() do { RENORM_HALF(x, x, S2A); RENORM_HALF(y, y, S2B); } while (0)

    // 17 rolled chunks of 32 steps (steps 0..543)
#pragma unroll 1
    for (int c = 0; c < 17; ++c) {
        const int cb = c * CHUNK;
#pragma unroll
        for (int s = 0; s < CHUNK; ++s) STEP(cb, s);
        RENORM();
    }
    // tail: steps 544..574 (31 steps); prefetch reads hit zero-padded xs
#pragma unroll
    for (int s = 0; s < 31; ++s) STEP(544, s);

    if (lane == 63) {
        float DA = ((float)S2A - log2f(prev2.x)) * LN2;
        float DB = ((float)S2B - log2f(prev2.y)) * LN2;
        out[b * NFILT + fA] = DA * (1.0f / (float)T_LEN);
        out[b * NFILT + fB] = DB * (1.0f / (float)T_LEN);
    }
#undef STEP
#undef RENORM_HALF
#undef RENORM
}

extern "C" void kernel_launch(void* const* d_in, const int* in_sizes, int n_in,
                              void* d_out, int out_size, void* d_ws, size_t ws_size,
                              hipStream_t stream) {
    const float* x      = (const float*)d_in[0];
    const float* protos = (const float*)d_in[1];
    float* out          = (float*)d_out;

    dim3 grid(NBATCH * 4);   // 256 blocks; 4 waves/block = 1 wave/SIMD
    dim3 block(256);         // each wave: 2 problems (f, f+16), same b
    hipLaunchKernelGGL(dtw_kernel, grid, block, 0, stream, x, protos, out);
}